// Round 20
// baseline (464.373 us; speedup 1.0000x reference)
//
#include <hip/hip_runtime.h>
#include <math.h>

// LinearAttention: b=32, c=128, h=w=128 (n=16384), heads=4, dim_head=32.
// Split-bf16 MFMA (3-term AhBh+AhBl+AlBh, fp32 acc).
//   wsplit: Wqkv -> bf16 hi/lo (RNE) in ws.
//   K1 (512 thr, 1 block/CU): W slab (rows 128..383) in LDS; per t-iter:
//       stage xT -> k/v GEMM -> exp/pack -> S-accum MFMA. LDS = 160 KB.
//   K1b: ctx reduce -> ctxF fp32.   MK: M = Wout·ctx -> Mh/Ml.
//   K2t (1024 thr = 16 waves, 1 block/CU): Wq + M[b] slabs (128 KB) in LDS;
//       32 iters x 64 p: stage xT -> q GEMM (wave = head x p-quarter) ->
//       in-reg softmax -> qs overlay -> y GEMM (wave = o-tile x p-half,
//       all-LDS A) -> LN -> store. LDS 160 KB.

#define NCHUNK 64

typedef __attribute__((ext_vector_type(8))) short short8;
typedef __attribute__((ext_vector_type(4))) float f32x4;

__device__ __forceinline__ uint bf16r(float f) {
    uint u = __float_as_uint(f);
    return (u + 0x7FFFu + ((u >> 16) & 1u)) >> 16;   // RNE
}
__device__ __forceinline__ float bf16f(uint h) { return __uint_as_float(h << 16); }
__device__ __forceinline__ uint2 bsplit(float f) {
    uint h = bf16r(f);
    float r = f - bf16f(h);
    return make_uint2(h, bf16r(r));
}
// truncation split (runtime data): 5 VALU ops.
__device__ __forceinline__ uint2 bsplit_t(float f) {
    uint u = __float_as_uint(f);
    uint uh = u & 0xFFFF0000u;
    float r = f - __uint_as_float(uh);
    return make_uint2(uh >> 16, __float_as_uint(r) >> 16);
}
__device__ __forceinline__ uint bpack_t(float f) {
    uint u = __float_as_uint(f);
    uint uh = u & 0xFFFF0000u;
    float r = f - __uint_as_float(uh);
    return (uh >> 16) | (__float_as_uint(r) & 0xFFFF0000u);
}
__device__ __forceinline__ short8 lo8(uint4 a, uint4 b) {
    uint4 r;
    r.x = (a.x & 0xFFFFu) | (a.y << 16);
    r.y = (a.z & 0xFFFFu) | (a.w << 16);
    r.z = (b.x & 0xFFFFu) | (b.y << 16);
    r.w = (b.z & 0xFFFFu) | (b.w << 16);
    return __builtin_bit_cast(short8, r);
}
__device__ __forceinline__ short8 hi8(uint4 a, uint4 b) {
    uint4 r;
    r.x = (a.x >> 16) | (a.y & 0xFFFF0000u);
    r.y = (a.z >> 16) | (a.w & 0xFFFF0000u);
    r.z = (b.x >> 16) | (b.y & 0xFFFF0000u);
    r.w = (b.z >> 16) | (b.w & 0xFFFF0000u);
    return __builtin_bit_cast(short8, r);
}

__global__ __launch_bounds__(256)
void wsplit(const float* __restrict__ W, ushort* __restrict__ Wh,
            ushort* __restrict__ Wl, int n)
{
    const int base = (blockIdx.x * 256 + threadIdx.x) * 4;
    if (base + 3 < n) {
        const float4 f = *(const float4*)(W + base);
        const uint2 a = bsplit(f.x), b2 = bsplit(f.y), c = bsplit(f.z), d = bsplit(f.w);
        ushort4 hh; hh.x = (ushort)a.x; hh.y = (ushort)b2.x; hh.z = (ushort)c.x; hh.w = (ushort)d.x;
        ushort4 ll; ll.x = (ushort)a.y; ll.y = (ushort)b2.y; ll.z = (ushort)c.y; ll.w = (ushort)d.y;
        *(ushort4*)(Wh + base) = hh;
        *(ushort4*)(Wl + base) = ll;
    }
}

#define MFMA(A, B, C) __builtin_amdgcn_mfma_f32_16x16x32_bf16((A), (B), (C), 0, 0, 0)

// =====================  K1: 512 threads, W in LDS (unchanged)  =====================
__global__ __launch_bounds__(512, 1)
void la_k1(const float* __restrict__ x,
           const ushort* __restrict__ Wh, const ushort* __restrict__ Wl,
           float* __restrict__ Spart, float* __restrict__ Zpart)
{
    __shared__ __align__(16) char smb[163840];

    const int tid = threadIdx.x;
    const int b = blockIdx.y, chunk = blockIdx.x;
    const int w = tid >> 6, l = tid & 63;        // 8 waves
    const int l15 = l & 15, lg = l >> 4;

    // ---- prologue: stage W rows 128..383 (h+l) into LDS, swizzled ----
    {
#pragma unroll
        for (int it = 0; it < 16; ++it) {
            const int q = tid + 512 * it;        // 0..8191 16B-quads
            const int region = q >> 12;          // 0 = h, 1 = l
            const int lin = (q & 4095) * 16;
            const int r = lin >> 8;
            const int dst = (region << 16) + (lin ^ ((r & 7) << 4));
            const ushort* src = (region ? Wl : Wh) + 128 * 128 + (lin >> 1);
            *(uint4*)(&smb[dst]) = *(const uint4*)src;
        }
    }

    f32x4 s2[2];
#pragma unroll
    for (int i = 0; i < 2; ++i) s2[i] = (f32x4){0.f, 0.f, 0.f, 0.f};
    float zrow[4];
#pragma unroll
    for (int i = 0; i < 4; ++i) zrow[i] = 0.f;

    const int hh = w >> 1, eh = w & 1;

    for (int t = 0; t < 8; ++t) {
        const int p0 = chunk * 256 + t * 32;
        {
            const float* xb = x + (size_t)b * 128 * 16384 + p0;
            const int cp = tid >> 3, j = tid & 7;
            const int pb = j * 4, c = cp * 2;
            const float4 a = *(const float4*)(xb + (size_t)c * 16384 + pb);
            const float4 bq = *(const float4*)(xb + (size_t)(c + 1) * 16384 + pb);
            const float av[4] = {a.x, a.y, a.z, a.w};
            const float bv[4] = {bq.x, bq.y, bq.z, bq.w};
#pragma unroll
            for (int pp = 0; pp < 4; ++pp) {
                const uint2 s0 = bsplit_t(av[pp]);
                const uint2 s1 = bsplit_t(bv[pp]);
                const int p = pb + pp;
                const int byt = (p * 256 + c * 2) ^ (((p ^ (p >> 3)) & 7) << 4);
                *(uint*)(&smb[131072 + byt])        = s0.x | (s1.x << 16);
                *(uint*)(&smb[131072 + 8192 + byt]) = s0.y | (s1.y << 16);
            }
        }
        __syncthreads();

        f32x4 acc[2][2];
#pragma unroll
        for (int rt = 0; rt < 2; ++rt)
#pragma unroll
            for (int ct = 0; ct < 2; ++ct) acc[rt][ct] = (f32x4){0.f, 0.f, 0.f, 0.f};
#pragma unroll
        for (int ks = 0; ks < 4; ++ks) {
            short8 Bh[2], Bl[2];
#pragma unroll
            for (int ct = 0; ct < 2; ++ct) {
                const int p = ct * 16 + l15;
                const int byt = (p * 256 + (ks * 32 + lg * 8) * 2) ^ (((p ^ (p >> 3)) & 7) << 4);
                Bh[ct] = *(const short8*)(&smb[131072 + byt]);
                Bl[ct] = *(const short8*)(&smb[131072 + 8192 + byt]);
            }
#pragma unroll
            for (int rt = 0; rt < 2; ++rt) {
                const int r = (w + rt * 8) * 16 + l15;
                const int abyt = (r * 256 + (ks * 32 + lg * 8) * 2) ^ ((r & 7) << 4);
                const short8 Ah_ = *(const short8*)(&smb[abyt]);
                const short8 Al_ = *(const short8*)(&smb[65536 + abyt]);
#pragma unroll
                for (int ct = 0; ct < 2; ++ct) {
                    acc[rt][ct] = MFMA(Ah_, Bh[ct], acc[rt][ct]);
                    acc[rt][ct] = MFMA(Ah_, Bl[ct], acc[rt][ct]);
                    acc[rt][ct] = MFMA(Al_, Bh[ct], acc[rt][ct]);
                }
            }
        }
        __syncthreads();

#pragma unroll
        for (int rt = 0; rt < 2; ++rt) {
            const bool isk = (rt == 0);
#pragma unroll
            for (int ct = 0; ct < 2; ++ct) {
                const int p = ct * 16 + l15;
#pragma unroll
                for (int i = 0; i < 4; ++i) {
                    float val = acc[rt][ct][i];
                    if (isk) {
                        val = expf(val);
                        zrow[i] += val;
                    }
                    const int r = w * 16 + lg * 4 + i;
                    const int byt = (r * 128 + p * 4) ^ ((r & 7) << 4);
                    *(uint*)(&smb[131072 + (isk ? 0 : 16384) + byt]) = bpack_t(val);
                }
            }
        }
        __syncthreads();

        {
            short8 A2h[2], A2l[2], B2h, B2l;
#pragma unroll
            for (int rt2 = 0; rt2 < 2; ++rt2) {
                const int r = hh * 32 + rt2 * 16 + l15;
                const int b0 = (r * 128 + lg * 32) ^ ((r & 7) << 4);
                const int b1 = (r * 128 + lg * 32 + 16) ^ ((r & 7) << 4);
                const uint4 q0 = *(const uint4*)(&smb[131072 + b0]);
                const uint4 q1 = *(const uint4*)(&smb[131072 + b1]);
                A2h[rt2] = lo8(q0, q1);
                A2l[rt2] = hi8(q0, q1);
            }
            {
                const int rv = hh * 32 + eh * 16 + l15;
                const int c0 = (rv * 128 + lg * 32) ^ ((rv & 7) << 4);
                const int c1 = (rv * 128 + lg * 32 + 16) ^ ((rv & 7) << 4);
                const uint4 r0 = *(const uint4*)(&smb[131072 + 16384 + c0]);
                const uint4 r1 = *(const uint4*)(&smb[131072 + 16384 + c1]);
                B2h = lo8(r0, r1);
                B2l = hi8(r0, r1);
            }
#pragma unroll
            for (int rt2 = 0; rt2 < 2; ++rt2) {
                s2[rt2] = MFMA(A2h[rt2], B2h, s2[rt2]);
                s2[rt2] = MFMA(A2h[rt2], B2l, s2[rt2]);
                s2[rt2] = MFMA(A2l[rt2], B2h, s2[rt2]);
            }
        }
        __syncthreads();
    }

    const size_t sbase = (((size_t)b * NCHUNK + chunk) * 4 + hh) * 1024;
#pragma unroll
    for (int rt2 = 0; rt2 < 2; ++rt2)
#pragma unroll
        for (int i = 0; i < 4; ++i) {
            const int d = rt2 * 16 + lg * 4 + i;
            const int e = eh * 16 + l15;
            Spart[sbase + d * 32 + e] = s2[rt2][i];
        }

#pragma unroll
    for (int i = 0; i < 4; ++i) {
        float z = zrow[i];
        z += __shfl_xor(z, 1, 64);
        z += __shfl_xor(z, 2, 64);
        z += __shfl_xor(z, 4, 64);
        z += __shfl_xor(z, 8, 64);
        if (l15 == 0)
            Zpart[((size_t)b * NCHUNK + chunk) * 128 + w * 16 + lg * 4 + i] = z;
    }
}

// K1b: ctx reduce -> fp32 ctxF[b][h][d][e]
__global__ __launch_bounds__(256, 1)
void la_k1_reduce(const float* __restrict__ Spart, const float* __restrict__ Zpart,
                  float* __restrict__ ctxF)
{
    const int tid = threadIdx.x;
    const int b  = blockIdx.x >> 2;
    const int hh = blockIdx.x & 3;
    const int d  = tid >> 3;
    const int e0 = (tid & 7) << 2;
    float sx = 0.f, sy = 0.f, sz = 0.f, sw = 0.f, z = 0.f;
    for (int ch = 0; ch < NCHUNK; ++ch) {
        const size_t base = (((size_t)b * NCHUNK + ch) * 4 + hh) * 32 + d;
        const float4 v = *(const float4*)(Spart + base * 32 + e0);
        sx += v.x; sy += v.y; sz += v.z; sw += v.w;
        z += Zpart[base];
    }
    const float inv = 1.0f / (z * 16384.0f);
    float4 r; r.x = sx * inv; r.y = sy * inv; r.z = sz * inv; r.w = sw * inv;
    *(float4*)(ctxF + ((((size_t)b * 4 + hh) * 32 + d) << 5) + e0) = r;
}

// MK: M[b][o][h*32+d] = sum_e Wout[o][h*32+e] * ctxF[b][h][d][e]; RNE split.
__global__ __launch_bounds__(256, 1)
void la_mk(const float* __restrict__ Wout, const float* __restrict__ ctxF,
           ushort* __restrict__ Mh, ushort* __restrict__ Ml)
{
    __shared__ float ctxs[4096];   // [h][d][e]
    const int b = blockIdx.x;
    const int tid = threadIdx.x;
#pragma unroll
    for (int i = 0; i < 4; ++i) {
        const int idx = (tid + 256 * i) * 4;
        *(float4*)(ctxs + idx) = *(const float4*)(ctxF + (size_t)b * 4096 + idx);
    }
    __syncthreads();
    const int cp = tid & 127;
    const int dh = tid >> 7;
#pragma unroll
    for (int hq = 0; hq < 2; ++hq) {
        const int h = dh * 2 + hq;
        float wrow[32];
#pragma unroll
        for (int e4 = 0; e4 < 8; ++e4) {
            const float4 wv = *(const float4*)(Wout + cp * 128 + h * 32 + e4 * 4);
            wrow[e4 * 4 + 0] = wv.x; wrow[e4 * 4 + 1] = wv.y;
            wrow[e4 * 4 + 2] = wv.z; wrow[e4 * 4 + 3] = wv.w;
        }
        for (int d = 0; d < 32; ++d) {
            float m = 0.f;
#pragma unroll
            for (int e = 0; e < 32; ++e)
                m += wrow[e] * ctxs[h * 1024 + d * 32 + e];
            const uint2 s = bsplit(m);
            const size_t mo = (size_t)b * 16384 + cp * 128 + h * 32 + d;
            Mh[mo] = (ushort)s.x;
            Ml[mo] = (ushort)s.y;
        }
    }
}

// =====================  K2t: 1024 threads (16 waves), Wq + M[b] in LDS  =====================
// LDS (163840 B):
//   [0,32768):        WqH rows 0..127, byte = (r*256+k*2) ^ ((r&7)<<4)
//   [32768,65536):    WqL
//   [65536,98304):    MH rows 0..127 (k = h*32+d), same swizzle
//   [98304,131072):   ML
//   [131072,147456):  xTh [64p][128c] xswz64   -> qsh [4sh][64p][32d] qswz
//   [147456,163840):  xTl                      -> qsl
//   lnred: [131072,135168) floats [64p][8ot][2] (after y GEMM barrier)
__device__ __forceinline__ int xswz64(int p, int cbyte) {
    return (p * 256 + cbyte) ^ (((p ^ (p >> 3)) & 7) << 4);
}
__device__ __forceinline__ int qswz(int p, int off) {
    return (p * 64 + off) ^ (((p >> 1) & 3) << 4);
}

__global__ __launch_bounds__(1024, 1)
void la_k2t(const float* __restrict__ x,
            const ushort* __restrict__ Wqh, const ushort* __restrict__ Wql,
            const ushort* __restrict__ Mh, const ushort* __restrict__ Ml,
            const float* __restrict__ bout, const float* __restrict__ g,
            float* __restrict__ outg)
{
    __shared__ __align__(16) char smb[163840];

    const int tid = threadIdx.x;
    const int b = blockIdx.y, blk = blockIdx.x;   // 8 blocks per batch
    const int w = tid >> 6, l = tid & 63;         // 16 waves
    const int l15 = l & 15, lg = l >> 4;
    const int hq = w >> 2, pq = w & 3;            // q phase: head, p-quarter
    const int ot = w >> 1, ph2 = w & 1;           // y phase: o-tile, p-half

    // ---- prologue: stage Wq (rows 0..127) + M[b] h/l into LDS ----
    {
        const ushort* mhb = Mh + (size_t)b * 16384;
        const ushort* mlb = Ml + (size_t)b * 16384;
#pragma unroll
        for (int it = 0; it < 8; ++it) {
            const int q = tid + 1024 * it;        // 0..8191 quads
            const int plane = q >> 11;            // 0=WqH 1=WqL 2=MH 3=ML
            const int lin = (q & 2047) * 16;
            const int r = lin >> 8;
            const int dst = plane * 32768 + (lin ^ ((r & 7) << 4));
            const ushort* src = (plane == 0 ? Wqh : plane == 1 ? Wql
                               : plane == 2 ? mhb : mlb) + (lin >> 1);
            *(uint4*)(&smb[dst]) = *(const uint4*)src;
        }
    }

    // bias/gain for this wave's o-tile (y phase)
    const float4 bo = *(const float4*)(bout + ot * 16 + lg * 4);
    const float4 gv = *(const float4*)(g + ot * 16 + lg * 4);

    for (int it = 0; it < 32; ++it) {
        const int p0 = blk * 2048 + it * 64;

        // ---- phase 1: stage x[128c][64p] -> xTh/xTl (1024 thr: 8 floats ea) ----
        {
            const float* xb = x + (size_t)b * 128 * 16384 + p0;
            const int j = tid & 15, cq = tid >> 4;    // j: p-quad, cq: c-pair 0..63
            const int pb = j * 4, c = cq * 2;
            const float4 a = *(const float4*)(xb + (size_t)c * 16384 + pb);
            const float4 bq = *(const float4*)(xb + (size_t)(c + 1) * 16384 + pb);
            const float av[4] = {a.x, a.y, a.z, a.w};
            const float bv[4] = {bq.x, bq.y, bq.z, bq.w};
#pragma unroll
            for (int pp = 0; pp < 4; ++pp) {
                const uint2 s0 = bsplit_t(av[pp]);
                const uint2 s1 = bsplit_t(bv[pp]);
                const int p = pb + pp;
                const int byt = xswz64(p, c * 2);
                *(uint*)(&smb[131072 + byt]) = s0.x | (s1.x << 16);
                *(uint*)(&smb[147456 + byt]) = s0.y | (s1.y << 16);
            }
        }
        __syncthreads();   // bar1: xT ready

        // ---- phase 2: q GEMM: wave (hq,pq) -> rows 32hq..+31 x 16 p ----
        f32x4 qacc[2];
        qacc[0] = (f32x4){0.f, 0.f, 0.f, 0.f};
        qacc[1] = (f32x4){0.f, 0.f, 0.f, 0.f};
        const int pQ = pq * 16 + l15;
#pragma unroll
        for (int ks = 0; ks < 4; ++ks) {
            const int byt = xswz64(pQ, (ks * 32 + lg * 8) * 2);
            const short8 Bh_ = *(const short8*)(&smb[131072 + byt]);
            const short8 Bl_ = *(const short8*)(&smb[147456 + byt]);
#pragma unroll
            for (int t_ = 0; t_ < 2; ++t_) {
                const int r = hq * 32 + t_ * 16 + l15;
                const int abyt = (r * 256 + (ks * 32 + lg * 8) * 2) ^ ((r & 7) << 4);
                const short8 Ah_ = *(const short8*)(&smb[abyt]);
                const short8 Al_ = *(const short8*)(&smb[32768 + abyt]);
                qacc[t_] = MFMA(Ah_, Bh_, qacc[t_]);
                qacc[t_] = MFMA(Ah_, Bl_, qacc[t_]);
                qacc[t_] = MFMA(Al_, Bh_, qacc[t_]);
            }
        }

        // ---- softmax over d (shfl over lg), no max-sub ----
        float vv[2][4];
        {
            float s = 0.f;
#pragma unroll
            for (int t_ = 0; t_ < 2; ++t_)
#pragma unroll
                for (int i = 0; i < 4; ++i) {
                    vv[t_][i] = expf(qacc[t_][i]);
                    s += vv[t_][i];
                }
            s += __shfl_xor(s, 16, 64);
            s += __shfl_xor(s, 32, 64);
            const float inv = 0.17677669529663687f / s;   // 32^-0.5 / s
#pragma unroll
            for (int t_ = 0; t_ < 2; ++t_)
#pragma unroll
                for (int i = 0; i < 4; ++i) vv[t_][i] *= inv;
        }
        __syncthreads();   // bar2: xT reads done -> qs overlay OK

        // ---- phase 3: write qs h/l ----
#pragma unroll
        for (int t_ = 0; t_ < 2; ++t_) {
            const uint2 a0 = bsplit_t(vv[t_][0]);
            const uint2 a1 = bsplit_t(vv[t_][1]);
            const uint2 a2 = bsplit_t(vv[t_][2]);
            const uint2 a3 = bsplit_t(vv[t_][3]);
            const int byt = hq * 4096 + qswz(pQ, (t_ * 16 + lg * 4) * 2);
            *(uint2*)(&smb[131072 + byt]) = make_uint2(a0.x | (a1.x << 16), a2.x | (a3.x << 16));
            *(uint2*)(&smb[147456 + byt]) = make_uint2(a0.y | (a1.y << 16), a2.y | (a3.y << 16));
        }
        __syncthreads();   // bar3: qs ready

        // ---- phase 4: y GEMM: wave (ot,ph2) -> 16 o x 32 p, A from M slab ----
        f32x4 yacc[2];
        yacc[0] = (f32x4){0.f, 0.f, 0.f, 0.f};
        yacc[1] = (f32x4){0.f, 0.f, 0.f, 0.f};
#pragma unroll
        for (int ks = 0; ks < 4; ++ks) {              // ks = head of k-range
            const int r = ot * 16 + l15;
            const int abyt = (r * 256 + (ks * 32 + lg * 8) * 2) ^ ((r & 7) << 4);
            const short8 Ah_ = *(const short8*)(&smb[65536 + abyt]);
            const short8 Al_ = *(const short8*)(&smb[98304 + abyt]);
#pragma unroll
            for (int ct = 0; ct < 2; ++ct) {
                const int p = ph2 * 32 + ct * 16 + l15;
                const int byt = ks * 4096 + qswz(p, lg * 16);
                const short8 Bh_ = *(const short8*)(&smb[131072 + byt]);
                const short8 Bl_ = *(const short8*)(&smb[147456 + byt]);
                yacc[ct] = MFMA(Ah_, Bh_, yacc[ct]);
                yacc[ct] = MFMA(Ah_, Bl_, yacc[ct]);
                yacc[ct] = MFMA(Al_, Bh_, yacc[ct]);
            }
        }
        __syncthreads();   // bar4: qs reads done -> lnred overlay OK

        // ---- phase 5: + bout, LayerNorm across o-tiles, * g, store ----
#pragma unroll
        for (int ct = 0; ct < 2; ++ct) {
            yacc[ct][0] += bo.x; yacc[ct][1] += bo.y;
            yacc[ct][2] += bo.z; yacc[ct][3] += bo.w;
        }
        float* lnred = (float*)(smb + 131072);   // [64p][8ot][2]
#pragma unroll
        for (int ct = 0; ct < 2; ++ct) {
            float s = 0.f, q = 0.f;
#pragma unroll
            for (int i = 0; i < 4; ++i) {
                const float yv = yacc[ct][i];
                s += yv; q += yv * yv;
            }
            s += __shfl_xor(s, 16, 64); q += __shfl_xor(q, 16, 64);
            s += __shfl_xor(s, 32, 64); q += __shfl_xor(q, 32, 64);
            if (lg == 0) {
                const int p = ph2 * 32 + ct * 16 + l15;
                lnred[(p * 8 + ot) * 2 + 0] = s;
                lnred[(p * 8 + ot) * 2 + 1] = q;
            }
        }
        __syncthreads();   // bar5: lnred ready
#pragma unroll
        for (int ct = 0; ct < 2; ++ct) {
            const int p = ph2 * 32 + ct * 16 + l15;
            float st = 0.f, qt = 0.f;
#pragma unroll
            for (int ww = 0; ww < 8; ++ww) {
                st += lnred[(p * 8 + ww) * 2 + 0];
                qt += lnred[(p * 8 + ww) * 2 + 1];
            }
            const float mean = st * (1.0f / 128.0f);
            const float var  = qt * (1.0f / 128.0f) - mean * mean;
            const float rstd = 1.0f / sqrtf(var + 1e-5f);
            const float gg[4] = {gv.x, gv.y, gv.z, gv.w};
#pragma unroll
            for (int i = 0; i < 4; ++i) {
                const int o = ot * 16 + lg * 4 + i;
                outg[((size_t)b * 128 + o) * 16384 + p0 + p] =
                    (yacc[ct][i] - mean) * rstd * gg[i];
            }
        }
        __syncthreads();   // bar6: lnred reads done before next stage overwrites
    }
}

extern "C" void kernel_launch(void* const* d_in, const int* in_sizes, int n_in,
                              void* d_out, int out_size, void* d_ws, size_t ws_size,
                              hipStream_t stream) {
    const float* x    = (const float*)d_in[0];
    const float* Wqkv = (const float*)d_in[1];
    const float* Wout = (const float*)d_in[2];
    const float* bout = (const float*)d_in[3];
    const float* g    = (const float*)d_in[4];
    float* out = (float*)d_out;

    float* Spart = (float*)d_ws;                              // 8388608 floats
    float* Zpart = Spart + (size_t)32 * NCHUNK * 4 * 32 * 32; // 262144 floats
    float* ctxF  = Zpart + (size_t)32 * NCHUNK * 4 * 32;      // 131072 floats
    ushort* Wqh  = (ushort*)(ctxF + (size_t)32 * 4096);       // 49152 each
    ushort* Wql  = Wqh + 384 * 128;
    // M reuses the dead Spart region (k1_reduce consumed it before la_mk runs)
    ushort* Mh   = (ushort*)Spart;                            // 32*16384
    ushort* Ml   = Mh + (size_t)32 * 16384;
    (void)in_sizes; (void)n_in; (void)out_size; (void)ws_size;

    wsplit<<<dim3(48), 256, 0, stream>>>(Wqkv, Wqh, Wql, 384 * 128);
    la_k1<<<dim3(NCHUNK, 32), 512, 0, stream>>>(x, Wqh, Wql, Spart, Zpart);
    la_k1_reduce<<<dim3(128), 256, 0, stream>>>(Spart, Zpart, ctxF);
    la_mk<<<dim3(32), 256, 0, stream>>>(Wout, ctxF, Mh, Ml);
    la_k2t<<<dim3(8, 32), 1024, 0, stream>>>(x, Wqh, Wql, Mh, Ml, bout, g, out);
}

// Round 21
// 451.504 us; speedup vs baseline: 1.0285x; 1.0285x over previous
//
#include <hip/hip_runtime.h>
#include <math.h>

// LinearAttention: b=32, c=128, h=w=128 (n=16384), heads=4, dim_head=32.
// Split-bf16 MFMA (3-term AhBh+AhBl+AlBh, fp32 acc).
//   wsplit: Wqkv -> bf16 hi/lo (RNE) in ws.
//   K1 (512 thr, 1 block/CU): W slab (rows 128..383) in LDS; per t-iter:
//       stage xT -> k/v GEMM -> exp/pack -> S-accum MFMA. LDS = 160 KB.
//   K1b: ctx reduce -> ctxF fp32.   MK: M = Wout·ctx -> Mh/Ml.
//   K2s (512 thr, 1 block/CU, 8 blocks x 32 batches): Wq + M[b] slabs (128 KB)
//       staged to LDS once; 32 iters x 64 p: stage xT -> q GEMM -> in-reg
//       softmax -> qs overlay -> y GEMM (all-LDS A) -> LN -> store. 160 KB.
//   [round-19 verbatim — measured best 453.9 us]

#define NCHUNK 64

typedef __attribute__((ext_vector_type(8))) short short8;
typedef __attribute__((ext_vector_type(4))) float f32x4;

__device__ __forceinline__ uint bf16r(float f) {
    uint u = __float_as_uint(f);
    return (u + 0x7FFFu + ((u >> 16) & 1u)) >> 16;   // RNE
}
__device__ __forceinline__ float bf16f(uint h) { return __uint_as_float(h << 16); }
__device__ __forceinline__ uint2 bsplit(float f) {
    uint h = bf16r(f);
    float r = f - bf16f(h);
    return make_uint2(h, bf16r(r));
}
// truncation split (runtime data): 5 VALU ops.
__device__ __forceinline__ uint2 bsplit_t(float f) {
    uint u = __float_as_uint(f);
    uint uh = u & 0xFFFF0000u;
    float r = f - __uint_as_float(uh);
    return make_uint2(uh >> 16, __float_as_uint(r) >> 16);
}
__device__ __forceinline__ uint bpack_t(float f) {
    uint u = __float_as_uint(f);
    uint uh = u & 0xFFFF0000u;
    float r = f - __uint_as_float(uh);
    return (uh >> 16) | (__float_as_uint(r) & 0xFFFF0000u);
}
__device__ __forceinline__ short8 lo8(uint4 a, uint4 b) {
    uint4 r;
    r.x = (a.x & 0xFFFFu) | (a.y << 16);
    r.y = (a.z & 0xFFFFu) | (a.w << 16);
    r.z = (b.x & 0xFFFFu) | (b.y << 16);
    r.w = (b.z & 0xFFFFu) | (b.w << 16);
    return __builtin_bit_cast(short8, r);
}
__device__ __forceinline__ short8 hi8(uint4 a, uint4 b) {
    uint4 r;
    r.x = (a.x >> 16) | (a.y & 0xFFFF0000u);
    r.y = (a.z >> 16) | (a.w & 0xFFFF0000u);
    r.z = (b.x >> 16) | (b.y & 0xFFFF0000u);
    r.w = (b.z >> 16) | (b.w & 0xFFFF0000u);
    return __builtin_bit_cast(short8, r);
}

__global__ __launch_bounds__(256)
void wsplit(const float* __restrict__ W, ushort* __restrict__ Wh,
            ushort* __restrict__ Wl, int n)
{
    const int base = (blockIdx.x * 256 + threadIdx.x) * 4;
    if (base + 3 < n) {
        const float4 f = *(const float4*)(W + base);
        const uint2 a = bsplit(f.x), b2 = bsplit(f.y), c = bsplit(f.z), d = bsplit(f.w);
        ushort4 hh; hh.x = (ushort)a.x; hh.y = (ushort)b2.x; hh.z = (ushort)c.x; hh.w = (ushort)d.x;
        ushort4 ll; ll.x = (ushort)a.y; ll.y = (ushort)b2.y; ll.z = (ushort)c.y; ll.w = (ushort)d.y;
        *(ushort4*)(Wh + base) = hh;
        *(ushort4*)(Wl + base) = ll;
    }
}

#define MFMA(A, B, C) __builtin_amdgcn_mfma_f32_16x16x32_bf16((A), (B), (C), 0, 0, 0)

// =====================  K1: 512 threads, W in LDS  =====================
__global__ __launch_bounds__(512, 1)
void la_k1(const float* __restrict__ x,
           const ushort* __restrict__ Wh, const ushort* __restrict__ Wl,
           float* __restrict__ Spart, float* __restrict__ Zpart)
{
    __shared__ __align__(16) char smb[163840];

    const int tid = threadIdx.x;
    const int b = blockIdx.y, chunk = blockIdx.x;
    const int w = tid >> 6, l = tid & 63;        // 8 waves
    const int l15 = l & 15, lg = l >> 4;

    // ---- prologue: stage W rows 128..383 (h+l) into LDS, swizzled ----
    {
#pragma unroll
        for (int it = 0; it < 16; ++it) {
            const int q = tid + 512 * it;        // 0..8191 16B-quads
            const int region = q >> 12;          // 0 = h, 1 = l
            const int lin = (q & 4095) * 16;
            const int r = lin >> 8;
            const int dst = (region << 16) + (lin ^ ((r & 7) << 4));
            const ushort* src = (region ? Wl : Wh) + 128 * 128 + (lin >> 1);
            *(uint4*)(&smb[dst]) = *(const uint4*)src;
        }
    }

    f32x4 s2[2];
#pragma unroll
    for (int i = 0; i < 2; ++i) s2[i] = (f32x4){0.f, 0.f, 0.f, 0.f};
    float zrow[4];
#pragma unroll
    for (int i = 0; i < 4; ++i) zrow[i] = 0.f;

    const int hh = w >> 1, eh = w & 1;

    for (int t = 0; t < 8; ++t) {
        const int p0 = chunk * 256 + t * 32;
        {
            const float* xb = x + (size_t)b * 128 * 16384 + p0;
            const int cp = tid >> 3, j = tid & 7;
            const int pb = j * 4, c = cp * 2;
            const float4 a = *(const float4*)(xb + (size_t)c * 16384 + pb);
            const float4 bq = *(const float4*)(xb + (size_t)(c + 1) * 16384 + pb);
            const float av[4] = {a.x, a.y, a.z, a.w};
            const float bv[4] = {bq.x, bq.y, bq.z, bq.w};
#pragma unroll
            for (int pp = 0; pp < 4; ++pp) {
                const uint2 s0 = bsplit_t(av[pp]);
                const uint2 s1 = bsplit_t(bv[pp]);
                const int p = pb + pp;
                const int byt = (p * 256 + c * 2) ^ (((p ^ (p >> 3)) & 7) << 4);
                *(uint*)(&smb[131072 + byt])        = s0.x | (s1.x << 16);
                *(uint*)(&smb[131072 + 8192 + byt]) = s0.y | (s1.y << 16);
            }
        }
        __syncthreads();

        f32x4 acc[2][2];
#pragma unroll
        for (int rt = 0; rt < 2; ++rt)
#pragma unroll
            for (int ct = 0; ct < 2; ++ct) acc[rt][ct] = (f32x4){0.f, 0.f, 0.f, 0.f};
#pragma unroll
        for (int ks = 0; ks < 4; ++ks) {
            short8 Bh[2], Bl[2];
#pragma unroll
            for (int ct = 0; ct < 2; ++ct) {
                const int p = ct * 16 + l15;
                const int byt = (p * 256 + (ks * 32 + lg * 8) * 2) ^ (((p ^ (p >> 3)) & 7) << 4);
                Bh[ct] = *(const short8*)(&smb[131072 + byt]);
                Bl[ct] = *(const short8*)(&smb[131072 + 8192 + byt]);
            }
#pragma unroll
            for (int rt = 0; rt < 2; ++rt) {
                const int r = (w + rt * 8) * 16 + l15;
                const int abyt = (r * 256 + (ks * 32 + lg * 8) * 2) ^ ((r & 7) << 4);
                const short8 Ah_ = *(const short8*)(&smb[abyt]);
                const short8 Al_ = *(const short8*)(&smb[65536 + abyt]);
#pragma unroll
                for (int ct = 0; ct < 2; ++ct) {
                    acc[rt][ct] = MFMA(Ah_, Bh[ct], acc[rt][ct]);
                    acc[rt][ct] = MFMA(Ah_, Bl[ct], acc[rt][ct]);
                    acc[rt][ct] = MFMA(Al_, Bh[ct], acc[rt][ct]);
                }
            }
        }
        __syncthreads();

#pragma unroll
        for (int rt = 0; rt < 2; ++rt) {
            const bool isk = (rt == 0);
#pragma unroll
            for (int ct = 0; ct < 2; ++ct) {
                const int p = ct * 16 + l15;
#pragma unroll
                for (int i = 0; i < 4; ++i) {
                    float val = acc[rt][ct][i];
                    if (isk) {
                        val = expf(val);
                        zrow[i] += val;
                    }
                    const int r = w * 16 + lg * 4 + i;
                    const int byt = (r * 128 + p * 4) ^ ((r & 7) << 4);
                    *(uint*)(&smb[131072 + (isk ? 0 : 16384) + byt]) = bpack_t(val);
                }
            }
        }
        __syncthreads();

        {
            short8 A2h[2], A2l[2], B2h, B2l;
#pragma unroll
            for (int rt2 = 0; rt2 < 2; ++rt2) {
                const int r = hh * 32 + rt2 * 16 + l15;
                const int b0 = (r * 128 + lg * 32) ^ ((r & 7) << 4);
                const int b1 = (r * 128 + lg * 32 + 16) ^ ((r & 7) << 4);
                const uint4 q0 = *(const uint4*)(&smb[131072 + b0]);
                const uint4 q1 = *(const uint4*)(&smb[131072 + b1]);
                A2h[rt2] = lo8(q0, q1);
                A2l[rt2] = hi8(q0, q1);
            }
            {
                const int rv = hh * 32 + eh * 16 + l15;
                const int c0 = (rv * 128 + lg * 32) ^ ((rv & 7) << 4);
                const int c1 = (rv * 128 + lg * 32 + 16) ^ ((rv & 7) << 4);
                const uint4 r0 = *(const uint4*)(&smb[131072 + 16384 + c0]);
                const uint4 r1 = *(const uint4*)(&smb[131072 + 16384 + c1]);
                B2h = lo8(r0, r1);
                B2l = hi8(r0, r1);
            }
#pragma unroll
            for (int rt2 = 0; rt2 < 2; ++rt2) {
                s2[rt2] = MFMA(A2h[rt2], B2h, s2[rt2]);
                s2[rt2] = MFMA(A2h[rt2], B2l, s2[rt2]);
                s2[rt2] = MFMA(A2l[rt2], B2h, s2[rt2]);
            }
        }
        __syncthreads();
    }

    const size_t sbase = (((size_t)b * NCHUNK + chunk) * 4 + hh) * 1024;
#pragma unroll
    for (int rt2 = 0; rt2 < 2; ++rt2)
#pragma unroll
        for (int i = 0; i < 4; ++i) {
            const int d = rt2 * 16 + lg * 4 + i;
            const int e = eh * 16 + l15;
            Spart[sbase + d * 32 + e] = s2[rt2][i];
        }

#pragma unroll
    for (int i = 0; i < 4; ++i) {
        float z = zrow[i];
        z += __shfl_xor(z, 1, 64);
        z += __shfl_xor(z, 2, 64);
        z += __shfl_xor(z, 4, 64);
        z += __shfl_xor(z, 8, 64);
        if (l15 == 0)
            Zpart[((size_t)b * NCHUNK + chunk) * 128 + w * 16 + lg * 4 + i] = z;
    }
}

// K1b: ctx reduce -> fp32 ctxF[b][h][d][e]
__global__ __launch_bounds__(256, 1)
void la_k1_reduce(const float* __restrict__ Spart, const float* __restrict__ Zpart,
                  float* __restrict__ ctxF)
{
    const int tid = threadIdx.x;
    const int b  = blockIdx.x >> 2;
    const int hh = blockIdx.x & 3;
    const int d  = tid >> 3;
    const int e0 = (tid & 7) << 2;
    float sx = 0.f, sy = 0.f, sz = 0.f, sw = 0.f, z = 0.f;
    for (int ch = 0; ch < NCHUNK; ++ch) {
        const size_t base = (((size_t)b * NCHUNK + ch) * 4 + hh) * 32 + d;
        const float4 v = *(const float4*)(Spart + base * 32 + e0);
        sx += v.x; sy += v.y; sz += v.z; sw += v.w;
        z += Zpart[base];
    }
    const float inv = 1.0f / (z * 16384.0f);
    float4 r; r.x = sx * inv; r.y = sy * inv; r.z = sz * inv; r.w = sw * inv;
    *(float4*)(ctxF + ((((size_t)b * 4 + hh) * 32 + d) << 5) + e0) = r;
}

// MK: M[b][o][h*32+d] = sum_e Wout[o][h*32+e] * ctxF[b][h][d][e]; RNE split.
__global__ __launch_bounds__(256, 1)
void la_mk(const float* __restrict__ Wout, const float* __restrict__ ctxF,
           ushort* __restrict__ Mh, ushort* __restrict__ Ml)
{
    __shared__ float ctxs[4096];   // [h][d][e]
    const int b = blockIdx.x;
    const int tid = threadIdx.x;
#pragma unroll
    for (int i = 0; i < 4; ++i) {
        const int idx = (tid + 256 * i) * 4;
        *(float4*)(ctxs + idx) = *(const float4*)(ctxF + (size_t)b * 4096 + idx);
    }
    __syncthreads();
    const int cp = tid & 127;
    const int dh = tid >> 7;
#pragma unroll
    for (int hq = 0; hq < 2; ++hq) {
        const int h = dh * 2 + hq;
        float wrow[32];
#pragma unroll
        for (int e4 = 0; e4 < 8; ++e4) {
            const float4 wv = *(const float4*)(Wout + cp * 128 + h * 32 + e4 * 4);
            wrow[e4 * 4 + 0] = wv.x; wrow[e4 * 4 + 1] = wv.y;
            wrow[e4 * 4 + 2] = wv.z; wrow[e4 * 4 + 3] = wv.w;
        }
        for (int d = 0; d < 32; ++d) {
            float m = 0.f;
#pragma unroll
            for (int e = 0; e < 32; ++e)
                m += wrow[e] * ctxs[h * 1024 + d * 32 + e];
            const uint2 s = bsplit(m);
            const size_t mo = (size_t)b * 16384 + cp * 128 + h * 32 + d;
            Mh[mo] = (ushort)s.x;
            Ml[mo] = (ushort)s.y;
        }
    }
}

// =====================  K2s: 512 threads, Wq + M[b] in LDS  =====================
// LDS (163840 B):
//   [0,32768):        WqH rows 0..127, byte = (r*256+k*2) ^ ((r&7)<<4)
//   [32768,65536):    WqL
//   [65536,98304):    MH rows 0..127 (k = h*32+d), same swizzle
//   [98304,131072):   ML
//   [131072,147456):  xTh [64p][128c] xswz64   -> qsh [4sh][64p][32d] qswz
//   [147456,163840):  xTl                      -> qsl
//   lnred: [131072,135168) floats [64p][8w][2] (after y GEMM barrier)
__device__ __forceinline__ int xswz64(int p, int cbyte) {
    return (p * 256 + cbyte) ^ (((p ^ (p >> 3)) & 7) << 4);
}
__device__ __forceinline__ int qswz(int p, int off) {
    return (p * 64 + off) ^ (((p >> 1) & 3) << 4);
}

__global__ __launch_bounds__(512, 1)
void la_k2s(const float* __restrict__ x,
            const ushort* __restrict__ Wqh, const ushort* __restrict__ Wql,
            const ushort* __restrict__ Mh, const ushort* __restrict__ Ml,
            const float* __restrict__ bout, const float* __restrict__ g,
            float* __restrict__ outg)
{
    __shared__ __align__(16) char smb[163840];

    const int tid = threadIdx.x;
    const int b = blockIdx.y, blk = blockIdx.x;   // 8 blocks per batch
    const int w = tid >> 6, l = tid & 63;         // 8 waves
    const int l15 = l & 15, lg = l >> 4;
    const int hq = w >> 1, ph = w & 1;            // q phase: head, p-half

    // ---- prologue: stage Wq (rows 0..127) + M[b] h/l into LDS ----
    {
        const ushort* mhb = Mh + (size_t)b * 16384;
        const ushort* mlb = Ml + (size_t)b * 16384;
#pragma unroll
        for (int it = 0; it < 16; ++it) {
            const int q = tid + 512 * it;         // 0..8191 quads
            const int plane = q >> 11;            // 0=WqH 1=WqL 2=MH 3=ML
            const int lin = (q & 2047) * 16;
            const int r = lin >> 8;
            const int dst = plane * 32768 + (lin ^ ((r & 7) << 4));
            const ushort* src = (plane == 0 ? Wqh : plane == 1 ? Wql
                               : plane == 2 ? mhb : mlb) + (lin >> 1);
            *(uint4*)(&smb[dst]) = *(const uint4*)src;
        }
    }

    // bias/gain for this wave's o-tile (y phase: wave w owns o rows w*16..+15)
    const float4 bo = *(const float4*)(bout + w * 16 + lg * 4);
    const float4 gv = *(const float4*)(g + w * 16 + lg * 4);

    for (int it = 0; it < 32; ++it) {
        const int p0 = blk * 2048 + it * 64;

        // ---- phase 1: stage x[128c][64p] -> xTh/xTl (512 thr: 16 floats ea) ----
        {
            const float* xb = x + (size_t)b * 128 * 16384 + p0;
            const int j = tid & 15, gq = tid >> 4;    // j: p-quad, gq: c-block 0..31
            const int pb = j * 4, cb = gq * 4;
            const float4 xv0 = *(const float4*)(xb + (size_t)(cb + 0) * 16384 + pb);
            const float4 xv1 = *(const float4*)(xb + (size_t)(cb + 1) * 16384 + pb);
            const float4 xv2 = *(const float4*)(xb + (size_t)(cb + 2) * 16384 + pb);
            const float4 xv3 = *(const float4*)(xb + (size_t)(cb + 3) * 16384 + pb);
            float rc[4][4];
            rc[0][0] = xv0.x; rc[0][1] = xv0.y; rc[0][2] = xv0.z; rc[0][3] = xv0.w;
            rc[1][0] = xv1.x; rc[1][1] = xv1.y; rc[1][2] = xv1.z; rc[1][3] = xv1.w;
            rc[2][0] = xv2.x; rc[2][1] = xv2.y; rc[2][2] = xv2.z; rc[2][3] = xv2.w;
            rc[3][0] = xv3.x; rc[3][1] = xv3.y; rc[3][2] = xv3.z; rc[3][3] = xv3.w;
#pragma unroll
            for (int pp = 0; pp < 4; ++pp) {
                const uint2 s0 = bsplit_t(rc[0][pp]);
                const uint2 s1 = bsplit_t(rc[1][pp]);
                const uint2 s2u = bsplit_t(rc[2][pp]);
                const uint2 s3 = bsplit_t(rc[3][pp]);
                const int p = pb + pp;
                const int byt = xswz64(p, cb * 2);
                *(uint2*)(&smb[131072 + byt]) = make_uint2(s0.x | (s1.x << 16), s2u.x | (s3.x << 16));
                *(uint2*)(&smb[147456 + byt]) = make_uint2(s0.y | (s1.y << 16), s2u.y | (s3.y << 16));
            }
        }
        __syncthreads();   // bar1: xT ready

        // ---- phase 2: q GEMM: wave (hq,ph) -> rows 32hq..+31 x 32 p ----
        f32x4 qacc[2][2];
#pragma unroll
        for (int t_ = 0; t_ < 2; ++t_)
#pragma unroll
            for (int ct = 0; ct < 2; ++ct) qacc[t_][ct] = (f32x4){0.f, 0.f, 0.f, 0.f};
#pragma unroll
        for (int ks = 0; ks < 4; ++ks) {
            short8 Bh[2], Bl[2];
#pragma unroll
            for (int ct = 0; ct < 2; ++ct) {
                const int p = ph * 32 + ct * 16 + l15;
                const int byt = xswz64(p, (ks * 32 + lg * 8) * 2);
                Bh[ct] = *(const short8*)(&smb[131072 + byt]);
                Bl[ct] = *(const short8*)(&smb[147456 + byt]);
            }
#pragma unroll
            for (int t_ = 0; t_ < 2; ++t_) {
                const int r = hq * 32 + t_ * 16 + l15;
                const int abyt = (r * 256 + (ks * 32 + lg * 8) * 2) ^ ((r & 7) << 4);
                const short8 Ah_ = *(const short8*)(&smb[abyt]);
                const short8 Al_ = *(const short8*)(&smb[32768 + abyt]);
#pragma unroll
                for (int ct = 0; ct < 2; ++ct) {
                    qacc[t_][ct] = MFMA(Ah_, Bh[ct], qacc[t_][ct]);
                    qacc[t_][ct] = MFMA(Ah_, Bl[ct], qacc[t_][ct]);
                    qacc[t_][ct] = MFMA(Al_, Bh[ct], qacc[t_][ct]);
                }
            }
        }

        // ---- softmax over d (shfl over lg), no max-sub ----
        float vv[2][2][4];
#pragma unroll
        for (int ct = 0; ct < 2; ++ct) {
            float s = 0.f;
#pragma unroll
            for (int t_ = 0; t_ < 2; ++t_)
#pragma unroll
                for (int i = 0; i < 4; ++i) {
                    vv[ct][t_][i] = expf(qacc[t_][ct][i]);
                    s += vv[ct][t_][i];
                }
            s += __shfl_xor(s, 16, 64);
            s += __shfl_xor(s, 32, 64);
            const float inv = 0.17677669529663687f / s;   // 32^-0.5 / s
#pragma unroll
            for (int t_ = 0; t_ < 2; ++t_)
#pragma unroll
                for (int i = 0; i < 4; ++i) vv[ct][t_][i] *= inv;
        }
        __syncthreads();   // bar2: xT reads done -> qs overlay OK

        // ---- phase 3: write qs h/l ----
#pragma unroll
        for (int ct = 0; ct < 2; ++ct) {
            const int p = ph * 32 + ct * 16 + l15;
#pragma unroll
            for (int t_ = 0; t_ < 2; ++t_) {
                const uint2 a0 = bsplit_t(vv[ct][t_][0]);
                const uint2 a1 = bsplit_t(vv[ct][t_][1]);
                const uint2 a2 = bsplit_t(vv[ct][t_][2]);
                const uint2 a3 = bsplit_t(vv[ct][t_][3]);
                const int byt = hq * 4096 + qswz(p, (t_ * 16 + lg * 4) * 2);
                *(uint2*)(&smb[131072 + byt]) = make_uint2(a0.x | (a1.x << 16), a2.x | (a3.x << 16));
                *(uint2*)(&smb[147456 + byt]) = make_uint2(a0.y | (a1.y << 16), a2.y | (a3.y << 16));
            }
        }
        __syncthreads();   // bar3: qs ready

        // ---- phase 4: y GEMM: wave w -> o-tile w (16 o) x 64 p, A from M slab ----
        f32x4 yacc[4];
#pragma unroll
        for (int ct = 0; ct < 4; ++ct) yacc[ct] = (f32x4){0.f, 0.f, 0.f, 0.f};
#pragma unroll
        for (int ks = 0; ks < 4; ++ks) {              // ks = head of k-range
            const int r = w * 16 + l15;
            const int abyt = (r * 256 + (ks * 32 + lg * 8) * 2) ^ ((r & 7) << 4);
            const short8 Ah_ = *(const short8*)(&smb[65536 + abyt]);
            const short8 Al_ = *(const short8*)(&smb[98304 + abyt]);
#pragma unroll
            for (int ct = 0; ct < 4; ++ct) {
                const int p = ct * 16 + l15;
                const int byt = ks * 4096 + qswz(p, lg * 16);
                const short8 Bh_ = *(const short8*)(&smb[131072 + byt]);
                const short8 Bl_ = *(const short8*)(&smb[147456 + byt]);
                yacc[ct] = MFMA(Ah_, Bh_, yacc[ct]);
                yacc[ct] = MFMA(Ah_, Bl_, yacc[ct]);
                yacc[ct] = MFMA(Al_, Bh_, yacc[ct]);
            }
        }
        __syncthreads();   // bar4: qs reads done -> lnred overlay OK

        // ---- phase 5: + bout, LayerNorm across waves, * g, store ----
#pragma unroll
        for (int ct = 0; ct < 4; ++ct) {
            yacc[ct][0] += bo.x; yacc[ct][1] += bo.y;
            yacc[ct][2] += bo.z; yacc[ct][3] += bo.w;
        }
        float* lnred = (float*)(smb + 131072);   // [64p][8w][2]
#pragma unroll
        for (int ct = 0; ct < 4; ++ct) {
            float s = 0.f, q = 0.f;
#pragma unroll
            for (int i = 0; i < 4; ++i) {
                const float yv = yacc[ct][i];
                s += yv; q += yv * yv;
            }
            s += __shfl_xor(s, 16, 64); q += __shfl_xor(q, 16, 64);
            s += __shfl_xor(s, 32, 64); q += __shfl_xor(q, 32, 64);
            if (lg == 0) {
                const int p = ct * 16 + l15;
                lnred[(p * 8 + w) * 2 + 0] = s;
                lnred[(p * 8 + w) * 2 + 1] = q;
            }
        }
        __syncthreads();   // bar5: lnred ready
#pragma unroll
        for (int ct = 0; ct < 4; ++ct) {
            const int p = ct * 16 + l15;
            float st = 0.f, qt = 0.f;
#pragma unroll
            for (int ww = 0; ww < 8; ++ww) {
                st += lnred[(p * 8 + ww) * 2 + 0];
                qt += lnred[(p * 8 + ww) * 2 + 1];
            }
            const float mean = st * (1.0f / 128.0f);
            const float var  = qt * (1.0f / 128.0f) - mean * mean;
            const float rstd = 1.0f / sqrtf(var + 1e-5f);
            const float gg[4] = {gv.x, gv.y, gv.z, gv.w};
#pragma unroll
            for (int i = 0; i < 4; ++i) {
                const int o = w * 16 + lg * 4 + i;
                outg[((size_t)b * 128 + o) * 16384 + p0 + p] =
                    (yacc[ct][i] - mean) * rstd * gg[i];
            }
        }
        __syncthreads();   // bar6: lnred reads done before next stage overwrites
    }
}

extern "C" void kernel_launch(void* const* d_in, const int* in_sizes, int n_in,
                              void* d_out, int out_size, void* d_ws, size_t ws_size,
                              hipStream_t stream) {
    const float* x    = (const float*)d_in[0];
    const float* Wqkv = (const float*)d_in[1];
    const float* Wout = (const float*)d_in[2];
    const float* bout = (const float*)d_in[3];
    const float* g    = (const float*)d_in[4];
    float* out = (float*)d_out;

    float* Spart = (float*)d_ws;                              // 8388608 floats
    float* Zpart = Spart + (size_t)32 * NCHUNK * 4 * 32 * 32; // 262144 floats
    float* ctxF  = Zpart + (size_t)32 * NCHUNK * 4 * 32;      // 131072 floats
    ushort* Wqh  = (ushort*)(ctxF + (size_t)32 * 4096);       // 49152 each
    ushort* Wql  = Wqh + 384 * 128;
    // M reuses the dead Spart region (k1_reduce consumed it before la_mk runs)
    ushort* Mh   = (ushort*)Spart;                            // 32*16384
    ushort* Ml   = Mh + (size_t)32 * 16384;
    (void)in_sizes; (void)n_in; (void)out_size; (void)ws_size;

    wsplit<<<dim3(48), 256, 0, stream>>>(Wqkv, Wqh, Wql, 384 * 128);
    la_k1<<<dim3(NCHUNK, 32), 512, 0, stream>>>(x, Wqh, Wql, Spart, Zpart);
    la_k1_reduce<<<dim3(128), 256, 0, stream>>>(Spart, Zpart, ctxF);
    la_mk<<<dim3(32), 256, 0, stream>>>(Wout, ctxF, Mh, Ml);
    la_k2s<<<dim3(8, 32), 512, 0, stream>>>(x, Wqh, Wql, Mh, Ml, bout, g, out);
}